// Round 1
// baseline (1086.525 us; speedup 1.0000x reference)
//
#include <hip/hip_runtime.h>

#define BATCH 4
#define SEQ   4096
#define NEMBD 384
#define HDIM  64
#define QBLK  32
#define KBLK  64
#define PSCALE 0.125f   // 64^-0.5

// ---------------- QKV projection ----------------
// block = 256 threads (4 waves). Each wave handles 8 rows; block handles 32
// rows of x. Thread (h, rg): h = output column 0..63, rg = wave id.
// x row reads are wave-uniform addresses (broadcast, 1 L1 transaction);
// W reads are 256 B coalesced and L1/L2-resident (96 KB each).
__global__ __launch_bounds__(256) void qkv_proj_kernel(
    const float* __restrict__ x,
    const float* __restrict__ Wq,
    const float* __restrict__ Wk,
    const float* __restrict__ Wv,
    float* __restrict__ q,
    float* __restrict__ k,
    float* __restrict__ v)
{
    const int h  = threadIdx.x & 63;
    const int rg = threadIdx.x >> 6;          // wave id 0..3
    const long row0 = (long)blockIdx.x * 32 + rg * 8;

    float aq[8], ak[8], av[8];
#pragma unroll
    for (int r = 0; r < 8; ++r) { aq[r] = 0.f; ak[r] = 0.f; av[r] = 0.f; }

    const float* xb = x + row0 * NEMBD;
#pragma unroll 2
    for (int c4 = 0; c4 < NEMBD/4; ++c4) {
        float4 xv[8];
#pragma unroll
        for (int r = 0; r < 8; ++r)
            xv[r] = *(const float4*)(xb + r*NEMBD + c4*4);
#pragma unroll
        for (int j = 0; j < 4; ++j) {
            const int c = c4*4 + j;
            const float wq = Wq[c*HDIM + h];
            const float wk = Wk[c*HDIM + h];
            const float wv = Wv[c*HDIM + h];
#pragma unroll
            for (int r = 0; r < 8; ++r) {
                const float xc = (j==0)?xv[r].x:(j==1)?xv[r].y:(j==2)?xv[r].z:xv[r].w;
                aq[r] = fmaf(xc, wq, aq[r]);
                ak[r] = fmaf(xc, wk, ak[r]);
                av[r] = fmaf(xc, wv, av[r]);
            }
        }
    }
#pragma unroll
    for (int r = 0; r < 8; ++r) {
        const long o = (row0 + r)*HDIM + h;
        q[o] = aq[r];
        k[o] = ak[r];
        v[o] = av[r];
    }
}

// ---------------- causal flash attention (fp32, vector ALU) ----------------
// block = 256 threads handles QBLK=32 q-rows of one batch. 8 lanes per row:
// lane owns 8 of the 64 head dims. Dot closed by 3x shfl_xor inside the
// aligned 8-lane group. K/V tiles (KBLK=64 x 64 fp32 = 16 KB each) staged in
// LDS, fully coalesced float4 loads. Online softmax with rescale-on-new-max.
__global__ __launch_bounds__(256) void attn_kernel(
    const float* __restrict__ Q,
    const float* __restrict__ K,
    const float* __restrict__ V,
    float* __restrict__ out)
{
    __shared__ float Ks[KBLK][HDIM];
    __shared__ float Vs[KBLK][HDIM];

    const int tid = threadIdx.x;
    const int b   = blockIdx.x & 3;
    // reversed q-tile order: longest causal blocks launch first
    const int qt  = (SEQ/QBLK - 1) - (blockIdx.x >> 2);
    const int q0  = qt * QBLK;
    const int g   = tid >> 3;      // row within tile, 0..31
    const int sub = tid & 7;       // dim octet, 0..7
    const int row = q0 + g;

    const long qoff = ((long)b*SEQ + row)*HDIM + sub*8;
    const float4 qa = *(const float4*)(Q + qoff);
    const float4 qb = *(const float4*)(Q + qoff + 4);
    // fold the 1/sqrt(H) scale into q (exact: power of two)
    const float qr0 = qa.x*PSCALE, qr1 = qa.y*PSCALE, qr2 = qa.z*PSCALE, qr3 = qa.w*PSCALE;
    const float qr4 = qb.x*PSCALE, qr5 = qb.y*PSCALE, qr6 = qb.z*PSCALE, qr7 = qb.w*PSCALE;

    float o[8];
#pragma unroll
    for (int j = 0; j < 8; ++j) o[j] = 0.f;
    float m = -INFINITY;
    float l = 0.f;

    const float* Kb = K + (long)b*SEQ*HDIM;
    const float* Vb = V + (long)b*SEQ*HDIM;
    const int ntiles = (q0 + QBLK + KBLK - 1) / KBLK;

    for (int kt = 0; kt < ntiles; ++kt) {
        __syncthreads();
        {
            const float4* Kg = (const float4*)(Kb + (long)kt*KBLK*HDIM);
            const float4* Vg = (const float4*)(Vb + (long)kt*KBLK*HDIM);
            float4* KsV = (float4*)&Ks[0][0];
            float4* VsV = (float4*)&Vs[0][0];
#pragma unroll
            for (int i = 0; i < 4; ++i) {
                KsV[tid + i*256] = Kg[tid + i*256];
                VsV[tid + i*256] = Vg[tid + i*256];
            }
        }
        __syncthreads();

        const int lim = min(KBLK, row - kt*KBLK + 1);   // causal bound, uniform per 8-lane group
        for (int kk = 0; kk < lim; ++kk) {
            const float* kr = &Ks[kk][sub*8];
            const float4 k0 = *(const float4*)kr;
            const float4 k1 = *(const float4*)(kr + 4);
            // balanced partial dot (depth 4)
            float p0 = fmaf(qr1, k0.y, qr0*k0.x);
            float p1 = fmaf(qr3, k0.w, qr2*k0.z);
            float p2 = fmaf(qr5, k1.y, qr4*k1.x);
            float p3 = fmaf(qr7, k1.w, qr6*k1.z);
            float s = (p0 + p1) + (p2 + p3);
            // close the dot across the 8-lane group
            s += __shfl_xor(s, 1);
            s += __shfl_xor(s, 2);
            s += __shfl_xor(s, 4);

            const float* vr = &Vs[kk][sub*8];
            const float4 v0 = *(const float4*)vr;
            const float4 v1 = *(const float4*)(vr + 4);

            if (s > m) {            // rare after warm-up (~log T times per row)
                const float cr = __expf(m - s);   // expf(-inf)=0 handles first key
                l = fmaf(l, cr, 1.f);
                o[0] = fmaf(o[0], cr, v0.x);
                o[1] = fmaf(o[1], cr, v0.y);
                o[2] = fmaf(o[2], cr, v0.z);
                o[3] = fmaf(o[3], cr, v0.w);
                o[4] = fmaf(o[4], cr, v1.x);
                o[5] = fmaf(o[5], cr, v1.y);
                o[6] = fmaf(o[6], cr, v1.z);
                o[7] = fmaf(o[7], cr, v1.w);
                m = s;
            } else {
                const float p = __expf(s - m);
                l += p;
                o[0] = fmaf(p, v0.x, o[0]);
                o[1] = fmaf(p, v0.y, o[1]);
                o[2] = fmaf(p, v0.z, o[2]);
                o[3] = fmaf(p, v0.w, o[3]);
                o[4] = fmaf(p, v1.x, o[4]);
                o[5] = fmaf(p, v1.y, o[5]);
                o[6] = fmaf(p, v1.z, o[6]);
                o[7] = fmaf(p, v1.w, o[7]);
            }
        }
    }

    const float inv = 1.0f / l;
    const long ooff = ((long)b*SEQ + row)*HDIM + sub*8;
    float4 r0, r1;
    r0.x = o[0]*inv; r0.y = o[1]*inv; r0.z = o[2]*inv; r0.w = o[3]*inv;
    r1.x = o[4]*inv; r1.y = o[5]*inv; r1.z = o[6]*inv; r1.w = o[7]*inv;
    *(float4*)(out + ooff)     = r0;
    *(float4*)(out + ooff + 4) = r1;
}

extern "C" void kernel_launch(void* const* d_in, const int* in_sizes, int n_in,
                              void* d_out, int out_size, void* d_ws, size_t ws_size,
                              hipStream_t stream) {
    const float* x  = (const float*)d_in[0];
    const float* Wq = (const float*)d_in[1];
    const float* Wk = (const float*)d_in[2];
    const float* Wv = (const float*)d_in[3];
    float* out = (float*)d_out;

    float* qws = (float*)d_ws;                     // 4 MB
    const size_t per = (size_t)BATCH * SEQ * HDIM; // 1M floats each
    float* kws = qws + per;
    float* vws = kws + per;

    qkv_proj_kernel<<<BATCH*SEQ/32, 256, 0, stream>>>(x, Wq, Wk, Wv, qws, kws, vws);
    attn_kernel<<<BATCH*(SEQ/QBLK), 256, 0, stream>>>(qws, kws, vws, out);
}

// Round 4
// 486.231 us; speedup vs baseline: 2.2346x; 2.2346x over previous
//
#include <hip/hip_runtime.h>

#define BATCH 4
#define SEQ   4096
#define NEMBD 384
#define HDIM  64
#define QBLK  32
#define KBLK  64
// 64^-0.5 * log2(e): q pre-scaled so softmax works in exp2 domain
#define QSCALE 0.18033688011112042f
#define NEG_BIG (-1.0e30f)
#define EXP2F(x) __builtin_amdgcn_exp2f(x)

// ---------------- QKV projection ----------------
// 256 threads = 4 waves, each wave owns 4 rows; block = 16 rows. grid = 1024.
// x row reads are wave-uniform (broadcast); W reads coalesced, L2-hot.
__global__ __launch_bounds__(256) void qkv_proj_kernel(
    const float* __restrict__ x,
    const float* __restrict__ Wq,
    const float* __restrict__ Wk,
    const float* __restrict__ Wv,
    float* __restrict__ q,
    float* __restrict__ k,
    float* __restrict__ v)
{
    const int h  = threadIdx.x & 63;
    const int rg = threadIdx.x >> 6;          // wave id 0..3
    const long row0 = (long)blockIdx.x * 16 + rg * 4;

    float aq[4], ak[4], av[4];
#pragma unroll
    for (int r = 0; r < 4; ++r) { aq[r] = 0.f; ak[r] = 0.f; av[r] = 0.f; }

    const float* xb = x + row0 * NEMBD;
#pragma unroll 2
    for (int c4 = 0; c4 < NEMBD/4; ++c4) {
        float4 xv[4];
#pragma unroll
        for (int r = 0; r < 4; ++r)
            xv[r] = *(const float4*)(xb + r*NEMBD + c4*4);
#pragma unroll
        for (int j = 0; j < 4; ++j) {
            const int c = c4*4 + j;
            const float wq = Wq[c*HDIM + h];
            const float wk = Wk[c*HDIM + h];
            const float wv = Wv[c*HDIM + h];
#pragma unroll
            for (int r = 0; r < 4; ++r) {
                const float xc = (j==0)?xv[r].x:(j==1)?xv[r].y:(j==2)?xv[r].z:xv[r].w;
                aq[r] = fmaf(xc, wq, aq[r]);
                ak[r] = fmaf(xc, wk, ak[r]);
                av[r] = fmaf(xc, wv, av[r]);
            }
        }
    }
#pragma unroll
    for (int r = 0; r < 4; ++r) {
        const long o = (row0 + r)*HDIM + h;
        q[o] = aq[r];
        k[o] = ak[r];
        v[o] = av[r];
    }
}

// ---------------- causal flash attention, split-K x2, fp32 VALU ----------------
// block = 256 threads = 32 q-rows x 8 lanes/row. Part p processes K-tiles
// kt % 2 == p; partial (o,m,l) written to workspace, merged by combine_kernel.
// Inner loop: chunks of 4 keys (independent dots/shfls/exps = ILP), branchless
// causal mask, wave-uniform __any() rescale branch (no divergence).

#define DOT8(KA, KB) \
    ((fmaf(qv1, KA.y, qv0*KA.x) + fmaf(qv3, KA.w, qv2*KA.z)) + \
     (fmaf(qv5, KB.y, qv4*KB.x) + fmaf(qv7, KB.w, qv6*KB.z)))

#define PV_ACC(P, VA, VB) \
    o0 = fmaf(P, VA.x, o0); o1 = fmaf(P, VA.y, o1); \
    o2 = fmaf(P, VA.z, o2); o3 = fmaf(P, VA.w, o3); \
    o4 = fmaf(P, VB.x, o4); o5 = fmaf(P, VB.y, o5); \
    o6 = fmaf(P, VB.z, o6); o7 = fmaf(P, VB.w, o7);

#define O_SCALE(S) \
    o0 *= S; o1 *= S; o2 *= S; o3 *= S; \
    o4 *= S; o5 *= S; o6 *= S; o7 *= S;

#define CHUNK_BODY(MASKED)                                                    \
  {                                                                           \
    const float4 ka0 = *(const float4*)&Ks[kk+0][sub8];                       \
    const float4 kb0 = *(const float4*)&Ks[kk+0][sub8+4];                     \
    const float4 ka1 = *(const float4*)&Ks[kk+1][sub8];                       \
    const float4 kb1 = *(const float4*)&Ks[kk+1][sub8+4];                     \
    const float4 ka2 = *(const float4*)&Ks[kk+2][sub8];                       \
    const float4 kb2 = *(const float4*)&Ks[kk+2][sub8+4];                     \
    const float4 ka3 = *(const float4*)&Ks[kk+3][sub8];                       \
    const float4 kb3 = *(const float4*)&Ks[kk+3][sub8+4];                     \
    float s0 = DOT8(ka0, kb0);                                                \
    float s1 = DOT8(ka1, kb1);                                                \
    float s2 = DOT8(ka2, kb2);                                                \
    float s3 = DOT8(ka3, kb3);                                                \
    s0 += __shfl_xor(s0, 1); s1 += __shfl_xor(s1, 1);                         \
    s2 += __shfl_xor(s2, 1); s3 += __shfl_xor(s3, 1);                         \
    s0 += __shfl_xor(s0, 2); s1 += __shfl_xor(s1, 2);                         \
    s2 += __shfl_xor(s2, 2); s3 += __shfl_xor(s3, 2);                         \
    s0 += __shfl_xor(s0, 4); s1 += __shfl_xor(s1, 4);                         \
    s2 += __shfl_xor(s2, 4); s3 += __shfl_xor(s3, 4);                         \
    if (MASKED) {                                                             \
      s0 = (kk+0 < lim) ? s0 : NEG_BIG;                                       \
      s1 = (kk+1 < lim) ? s1 : NEG_BIG;                                       \
      s2 = (kk+2 < lim) ? s2 : NEG_BIG;                                       \
      s3 = (kk+3 < lim) ? s3 : NEG_BIG;                                       \
    }                                                                         \
    const float cmax = fmaxf(fmaxf(s0, s1), fmaxf(s2, s3));                   \
    const float4 va0 = *(const float4*)&Vs[kk+0][sub8];                       \
    const float4 vb0 = *(const float4*)&Vs[kk+0][sub8+4];                     \
    const float4 va1 = *(const float4*)&Vs[kk+1][sub8];                       \
    const float4 vb1 = *(const float4*)&Vs[kk+1][sub8+4];                     \
    const float4 va2 = *(const float4*)&Vs[kk+2][sub8];                       \
    const float4 vb2 = *(const float4*)&Vs[kk+2][sub8+4];                     \
    const float4 va3 = *(const float4*)&Vs[kk+3][sub8];                       \
    const float4 vb3 = *(const float4*)&Vs[kk+3][sub8+4];                     \
    if (__any(cmax > m)) {                                                    \
      const float newm = fmaxf(m, cmax);                                      \
      const float scale = EXP2F(m - newm);                                    \
      m = newm;                                                               \
      const float p0 = EXP2F(s0 - m);                                         \
      const float p1 = EXP2F(s1 - m);                                         \
      const float p2 = EXP2F(s2 - m);                                         \
      const float p3 = EXP2F(s3 - m);                                         \
      l = fmaf(l, scale, (p0 + p1) + (p2 + p3));                              \
      O_SCALE(scale);                                                         \
      PV_ACC(p0, va0, vb0);                                                   \
      PV_ACC(p1, va1, vb1);                                                   \
      PV_ACC(p2, va2, vb2);                                                   \
      PV_ACC(p3, va3, vb3);                                                   \
    } else {                                                                  \
      const float p0 = EXP2F(s0 - m);                                         \
      const float p1 = EXP2F(s1 - m);                                         \
      const float p2 = EXP2F(s2 - m);                                         \
      const float p3 = EXP2F(s3 - m);                                         \
      l += (p0 + p1) + (p2 + p3);                                             \
      PV_ACC(p0, va0, vb0);                                                   \
      PV_ACC(p1, va1, vb1);                                                   \
      PV_ACC(p2, va2, vb2);                                                   \
      PV_ACC(p3, va3, vb3);                                                   \
    }                                                                         \
  }

__global__ __launch_bounds__(256, 4) void attn_kernel(
    const float* __restrict__ Q,
    const float* __restrict__ K,
    const float* __restrict__ V,
    float* __restrict__ opart,
    float* __restrict__ mlpart)
{
    __shared__ float Ks[KBLK][HDIM];
    __shared__ float Vs[KBLK][HDIM];

    const int gid  = blockIdx.x;
    const int part = gid & 1;
    const int b    = (gid >> 1) & 3;
    const int qt   = (SEQ/QBLK - 1) - (gid >> 3);   // longest work first
    const int q0   = qt * QBLK;
    const int tid  = threadIdx.x;
    const int g    = tid >> 3;       // row within tile, 0..31
    const int sub  = tid & 7;        // dim octet
    const int sub8 = sub * 8;
    const int row  = q0 + g;

    const long qoff = ((long)b*SEQ + row)*HDIM + sub8;
    const float4 qa = *(const float4*)(Q + qoff);
    const float4 qb = *(const float4*)(Q + qoff + 4);
    const float qv0 = qa.x*QSCALE, qv1 = qa.y*QSCALE, qv2 = qa.z*QSCALE, qv3 = qa.w*QSCALE;
    const float qv4 = qb.x*QSCALE, qv5 = qb.y*QSCALE, qv6 = qb.z*QSCALE, qv7 = qb.w*QSCALE;

    float o0=0.f,o1=0.f,o2=0.f,o3=0.f,o4=0.f,o5=0.f,o6=0.f,o7=0.f;
    float m = NEG_BIG;
    float l = 0.f;

    const float* Kb = K + (long)b*SEQ*HDIM;
    const float* Vb = V + (long)b*SEQ*HDIM;
    const int ntiles = (q0 + QBLK + KBLK - 1) / KBLK;

    for (int kt = part; kt < ntiles; kt += 2) {
        __syncthreads();
        {
            const float4* Kg = (const float4*)(Kb + (long)kt*KBLK*HDIM);
            const float4* Vg = (const float4*)(Vb + (long)kt*KBLK*HDIM);
            float4* KsV = (float4*)&Ks[0][0];
            float4* VsV = (float4*)&Vs[0][0];
#pragma unroll
            for (int i = 0; i < 4; ++i) {
                KsV[tid + i*256] = Kg[tid + i*256];
                VsV[tid + i*256] = Vg[tid + i*256];
            }
        }
        __syncthreads();

        if (kt*KBLK + KBLK <= q0) {
            // fully-causal tile: no masking
            const int lim = KBLK; (void)lim;
#pragma unroll 2
            for (int kk = 0; kk < KBLK; kk += 4) CHUNK_BODY(false)
        } else {
            // diagonal tile: per-row causal bound (>=1 for every row)
            const int lim   = row - kt*KBLK + 1;
            const int kkend = q0 + QBLK - kt*KBLK;   // lim of last row in block
            for (int kk = 0; kk < kkend; kk += 4) CHUNK_BODY(true)
        }
    }

    const long PER = (long)BATCH * SEQ * HDIM;
    float* op = opart + (long)part*PER + ((long)b*SEQ + row)*HDIM + sub8;
    float4 r0; r0.x = o0; r0.y = o1; r0.z = o2; r0.w = o3;
    float4 r1; r1.x = o4; r1.y = o5; r1.z = o6; r1.w = o7;
    *(float4*)op       = r0;
    *(float4*)(op + 4) = r1;
    if (sub == 0) {
        float2 ml; ml.x = m; ml.y = l;
        *(float2*)&mlpart[((long)part*BATCH*SEQ + (long)b*SEQ + row)*2] = ml;
    }
}

// ---------------- split-K combine ----------------
// thread = one (row, dim). m values are in log2 domain -> exp2 merge.
__global__ __launch_bounds__(256) void combine_kernel(
    const float* __restrict__ opart,
    const float* __restrict__ mlpart,
    float* __restrict__ out)
{
    const int tid  = threadIdx.x;
    const int d    = tid & 63;
    const int rsub = tid >> 6;                       // 0..3
    const long row = (long)blockIdx.x * 4 + rsub;    // 0..B*SEQ
    const long PER = (long)BATCH * SEQ * HDIM;

    const float o0 = opart[row*HDIM + d];
    const float o1 = opart[PER + row*HDIM + d];
    const float2 ml0 = *(const float2*)&mlpart[row*2];
    const float2 ml1 = *(const float2*)&mlpart[((long)BATCH*SEQ + row)*2];

    const float M  = fmaxf(ml0.x, ml1.x);
    const float e0 = EXP2F(ml0.x - M);
    const float e1 = EXP2F(ml1.x - M);
    const float L  = ml0.y*e0 + ml1.y*e1;
    out[row*HDIM + d] = (o0*e0 + o1*e1) / L;
}

extern "C" void kernel_launch(void* const* d_in, const int* in_sizes, int n_in,
                              void* d_out, int out_size, void* d_ws, size_t ws_size,
                              hipStream_t stream) {
    const float* x  = (const float*)d_in[0];
    const float* Wq = (const float*)d_in[1];
    const float* Wk = (const float*)d_in[2];
    const float* Wv = (const float*)d_in[3];
    float* out = (float*)d_out;

    const size_t PER = (size_t)BATCH * SEQ * HDIM;   // 1M floats
    float* qws    = (float*)d_ws;
    float* kws    = qws + PER;
    float* vws    = kws + PER;
    float* opart  = vws + PER;          // 2 * PER floats
    float* mlpart = opart + 2*PER;      // 2 * B*SEQ * 2 floats

    qkv_proj_kernel<<<BATCH*SEQ/16, 256, 0, stream>>>(x, Wq, Wk, Wv, qws, kws, vws);
    attn_kernel<<<2*BATCH*(SEQ/QBLK), 256, 0, stream>>>(qws, kws, vws, opart, mlpart);
    combine_kernel<<<BATCH*SEQ/4, 256, 0, stream>>>(opart, mlpart, out);
}

// Round 5
// 354.872 us; speedup vs baseline: 3.0617x; 1.3702x over previous
//
#include <hip/hip_runtime.h>

#define BATCH 4
#define SEQ   4096
#define NEMBD 384
#define HDIM  64
#define KBLK  64
#define QPW   32                 // q-rows per wave (2 lanes/row)
#define QBLKB 128                // q-rows per block (4 waves)
#define NQT   (SEQ/QBLKB)        // 32
// 64^-0.5 * log2(e): q pre-scaled so softmax works in exp2 domain
#define QSCALE 0.18033688011112042f
#define NEG_BIG (-1.0e30f)
#define EXP2F(x) __builtin_amdgcn_exp2f(x)

// ---------------- QKV projection (unchanged from round 4) ----------------
__global__ __launch_bounds__(256) void qkv_proj_kernel(
    const float* __restrict__ x,
    const float* __restrict__ Wq,
    const float* __restrict__ Wk,
    const float* __restrict__ Wv,
    float* __restrict__ q,
    float* __restrict__ k,
    float* __restrict__ v)
{
    const int h  = threadIdx.x & 63;
    const int rg = threadIdx.x >> 6;          // wave id 0..3
    const long row0 = (long)blockIdx.x * 16 + rg * 4;

    float aq[4], ak[4], av[4];
#pragma unroll
    for (int r = 0; r < 4; ++r) { aq[r] = 0.f; ak[r] = 0.f; av[r] = 0.f; }

    const float* xb = x + row0 * NEMBD;
#pragma unroll 2
    for (int c4 = 0; c4 < NEMBD/4; ++c4) {
        float4 xv[4];
#pragma unroll
        for (int r = 0; r < 4; ++r)
            xv[r] = *(const float4*)(xb + r*NEMBD + c4*4);
#pragma unroll
        for (int j = 0; j < 4; ++j) {
            const int c = c4*4 + j;
            const float wq = Wq[c*HDIM + h];
            const float wk = Wk[c*HDIM + h];
            const float wv = Wv[c*HDIM + h];
#pragma unroll
            for (int r = 0; r < 4; ++r) {
                const float xc = (j==0)?xv[r].x:(j==1)?xv[r].y:(j==2)?xv[r].z:xv[r].w;
                aq[r] = fmaf(xc, wq, aq[r]);
                ak[r] = fmaf(xc, wk, ak[r]);
                av[r] = fmaf(xc, wv, av[r]);
            }
        }
    }
#pragma unroll
    for (int r = 0; r < 4; ++r) {
        const long o = (row0 + r)*HDIM + h;
        q[o] = aq[r];
        k[o] = ak[r];
        v[o] = av[r];
    }
}

// ---------------- causal flash attention v3 ----------------
// 2 lanes per q-row (each owns 32 dims): dot = 32 chained FMA + 1 shfl_xor.
// Block = 4 waves x 32 rows = 128 q-rows; K/V tile 64x64 staged in LDS and
// shared by all 4 waves; per-wave tile skip for the causal stagger.
// Split-K x S (runtime), partials (o,m,l) merged by combine_kernel.

__device__ __forceinline__ float dot_half(const float4* Ks4, int kk, int sub,
                                          const float4 qv[8]) {
    const int rb = kk*16 + sub*8;
    float acc = 0.f;
#pragma unroll
    for (int j = 0; j < 8; ++j) {
        const float4 a = Ks4[rb + j];
        acc = fmaf(qv[j].x, a.x, acc);
        acc = fmaf(qv[j].y, a.y, acc);
        acc = fmaf(qv[j].z, a.z, acc);
        acc = fmaf(qv[j].w, a.w, acc);
    }
    return acc;
}

__device__ __forceinline__ void pv_acc(const float4* Vs4, int kk, int sub,
                                       float p, float4 ov[8]) {
    const int rb = kk*16 + sub*8;
#pragma unroll
    for (int j = 0; j < 8; ++j) {
        const float4 a = Vs4[rb + j];
        ov[j].x = fmaf(p, a.x, ov[j].x);
        ov[j].y = fmaf(p, a.y, ov[j].y);
        ov[j].z = fmaf(p, a.z, ov[j].z);
        ov[j].w = fmaf(p, a.w, ov[j].w);
    }
}

#define TWOKEY(MASKED)                                                        \
    {                                                                         \
      float s0 = dot_half(Ks4, kk+0, sub, qv);                                \
      float s1 = dot_half(Ks4, kk+1, sub, qv);                                \
      s0 += __shfl_xor(s0, 1);                                                \
      s1 += __shfl_xor(s1, 1);                                                \
      if (MASKED) {                                                           \
        s0 = (kk+0 < lim) ? s0 : NEG_BIG;                                     \
        s1 = (kk+1 < lim) ? s1 : NEG_BIG;                                     \
      }                                                                       \
      const float cmax = fmaxf(s0, s1);                                       \
      if (__any(cmax > m)) {                                                  \
        const float newm = fmaxf(m, cmax);                                    \
        const float scale = EXP2F(m - newm);                                  \
        m = newm;                                                             \
        l *= scale;                                                           \
        _Pragma("unroll")                                                     \
        for (int j = 0; j < 8; ++j) {                                         \
          ov[j].x *= scale; ov[j].y *= scale;                                 \
          ov[j].z *= scale; ov[j].w *= scale;                                 \
        }                                                                     \
      }                                                                       \
      const float p0 = EXP2F(s0 - m);                                         \
      const float p1 = EXP2F(s1 - m);                                         \
      l += p0 + p1;                                                           \
      pv_acc(Vs4, kk+0, sub, p0, ov);                                         \
      pv_acc(Vs4, kk+1, sub, p1, ov);                                         \
    }

__global__ __launch_bounds__(256, 4) void attn_kernel(
    const float* __restrict__ Q,
    const float* __restrict__ K,
    const float* __restrict__ V,
    float* __restrict__ opart,
    float* __restrict__ mlpart,
    const int S)
{
    __shared__ float Ks[KBLK][HDIM];
    __shared__ float Vs[KBLK][HDIM];

    const int gid  = blockIdx.x;
    const int part = gid % S;
    const int rest = gid / S;
    const int b    = rest & 3;
    const int qt   = (NQT - 1) - (rest >> 2);   // longest work first
    const int q0   = qt * QBLKB;
    const int tid  = threadIdx.x;
    const int w    = tid >> 6;                  // wave 0..3
    const int lane = tid & 63;
    const int g    = lane >> 1;                 // row within wave 0..31
    const int sub  = lane & 1;                  // dim half (32 floats)
    const int wmin = q0 + w * QPW;
    const int row  = wmin + g;

    // q fragment: this lane's 32 dims, pre-scaled into exp2 domain
    float4 qv[8];
    {
        const float* qp = Q + ((long)b*SEQ + row)*HDIM + sub*32;
#pragma unroll
        for (int j = 0; j < 8; ++j) {
            float4 t = *(const float4*)(qp + j*4);
            qv[j].x = t.x*QSCALE; qv[j].y = t.y*QSCALE;
            qv[j].z = t.z*QSCALE; qv[j].w = t.w*QSCALE;
        }
    }
    float4 ov[8];
#pragma unroll
    for (int j = 0; j < 8; ++j) { ov[j].x=0.f; ov[j].y=0.f; ov[j].z=0.f; ov[j].w=0.f; }
    float m = NEG_BIG, l = 0.f;

    const float* Kb = K + (long)b*SEQ*HDIM;
    const float* Vb = V + (long)b*SEQ*HDIM;
    const float4* Ks4 = (const float4*)&Ks[0][0];
    const float4* Vs4 = (const float4*)&Vs[0][0];
    const int ntiles = (q0 + QBLKB) / KBLK;     // 2*(qt+1)

    for (int kt = part; kt < ntiles; kt += S) {
        __syncthreads();
        {
            const float4* Kg = (const float4*)(Kb + (long)kt*KBLK*HDIM);
            const float4* Vg = (const float4*)(Vb + (long)kt*KBLK*HDIM);
            float4* Ksw = (float4*)&Ks[0][0];
            float4* Vsw = (float4*)&Vs[0][0];
#pragma unroll
            for (int i = 0; i < 4; ++i) {
                Ksw[tid + i*256] = Kg[tid + i*256];
                Vsw[tid + i*256] = Vg[tid + i*256];
            }
        }
        __syncthreads();

        const int base = kt * KBLK;
        if (base > wmin + (QPW-1)) continue;    // wave idle for this tile

        // every processed tile has base <= wmin  =>  lim >= 1 for all rows
        const int lim = row - base + 1;

        if (base + KBLK <= wmin) {
            // fully-causal tile: no masking
            for (int kk = 0; kk < KBLK; kk += 2) TWOKEY(false)
        } else {
            // diagonal tile: ke = wmax-base+1, even (wmin,base mult of 32)
            const int ke = wmin + QPW - base;
            for (int kk = 0; kk < ke; kk += 2) TWOKEY(true)
        }
    }

    const long rowoff = (long)b*SEQ + row;
    float* op = opart + ((long)part*BATCH*SEQ + rowoff)*HDIM + sub*32;
#pragma unroll
    for (int j = 0; j < 8; ++j) *(float4*)(op + j*4) = ov[j];
    if (sub == 0) {
        float2 ml; ml.x = m; ml.y = l;
        *(float2*)&mlpart[((long)part*BATCH*SEQ + rowoff)*2] = ml;
    }
}

// ---------------- split-K combine (S parts, exp2 domain) ----------------
__global__ __launch_bounds__(256) void combine_kernel(
    const float* __restrict__ opart,
    const float* __restrict__ mlpart,
    float* __restrict__ out,
    const int S)
{
    const int tid  = threadIdx.x;
    const int d    = tid & 63;
    const int rsub = tid >> 6;                      // 0..3
    const long row = (long)blockIdx.x * 4 + rsub;
    const long PERO = (long)BATCH * SEQ * HDIM;
    const long PERM = (long)BATCH * SEQ;

    float M = NEG_BIG;
    for (int p = 0; p < S; ++p)
        M = fmaxf(M, mlpart[((long)p*PERM + row)*2]);

    float L = 0.f, acc = 0.f;
    for (int p = 0; p < S; ++p) {
        const float2 ml = *(const float2*)&mlpart[((long)p*PERM + row)*2];
        const float e = EXP2F(ml.x - M);            // 0 for empty parts
        L   = fmaf(ml.y, e, L);
        acc = fmaf(opart[(long)p*PERO + row*HDIM + d], e, acc);
    }
    out[row*HDIM + d] = acc / L;
}

extern "C" void kernel_launch(void* const* d_in, const int* in_sizes, int n_in,
                              void* d_out, int out_size, void* d_ws, size_t ws_size,
                              hipStream_t stream) {
    const float* x  = (const float*)d_in[0];
    const float* Wq = (const float*)d_in[1];
    const float* Wk = (const float*)d_in[2];
    const float* Wv = (const float*)d_in[3];
    float* out = (float*)d_out;

    const size_t PER  = (size_t)BATCH * SEQ * HDIM;   // 1M floats
    const size_t PERM = (size_t)BATCH * SEQ;          // 16K rows

    // split-K factor adapted to workspace: need (3 + S)*PER + S*PERM*2 floats
    int S = 8;
    while (S > 1 && (3*PER + (size_t)S*PER + (size_t)S*PERM*2)*4 > ws_size) S >>= 1;

    float* qws    = (float*)d_ws;
    float* kws    = qws + PER;
    float* vws    = kws + PER;
    float* opart  = vws + PER;                 // S * PER floats
    float* mlpart = opart + (size_t)S*PER;     // S * PERM * 2 floats

    qkv_proj_kernel<<<BATCH*SEQ/16, 256, 0, stream>>>(x, Wq, Wk, Wv, qws, kws, vws);
    attn_kernel<<<S*BATCH*NQT, 256, 0, stream>>>(qws, kws, vws, opart, mlpart, S);
    combine_kernel<<<BATCH*SEQ/4, 256, 0, stream>>>(opart, mlpart, out, S);
}